// Round 1
// baseline (195.774 us; speedup 1.0000x reference)
//
#include <hip/hip_runtime.h>

// OneDilate: out[b,c,i,j] = 50 - 0.5 * sum_{10x10 clamped window} x
// Register-streaming, no LDS/barriers. Thread owns 4 consecutive output
// cols x 16-row band. Fully unrolled 25-row stream with 2-stage ping-pong
// load pipeline; 4 aligned float4 loads/row; scalar (SGPR) row addressing;
// tree-shaped horizontal sums; 10-deep float4 ring + running vertical sum.

#define IMG 512
#define OUTW 511
#define KS 10
#define MEAN 4
#define SUB 16                  // output rows per thread
#define TSTREAM (SUB + KS - 1)  // 25 streamed rows
#define NBANDS (IMG / (2 * SUB))  // 16 blocks along rows
#define NIMG 96                   // 32 * 3 images
#define NWG (NBANDS * NIMG)       // 1536 blocks (divisible by 8 XCDs)
#define CPX (NWG / 8)             // 192 blocks per XCD chunk

__global__ __launch_bounds__(256, 4) void onedilate_kernel(
    const float* __restrict__ x, float* __restrict__ out)
{
    // Bijective XCD-aware swizzle: consecutive dispatch ids (one XCD) get a
    // contiguous chunk of (band, image) work -> vertical halo rows hit L2.
    const int lin = blockIdx.y * NBANDS + blockIdx.x;
    const int swz = (lin & 7) * CPX + (lin >> 3);
    const int bx  = swz & (NBANDS - 1);   // row band
    const int bc  = swz >> 4;             // image index (NBANDS == 16)

    const int tid = threadIdx.x;
    const int j   = tid & 127;            // col group: output cols 4j..4j+3
    const int sub = __builtin_amdgcn_readfirstlane(tid >> 7);  // wave-uniform
    const int rb  = bx * (2 * SUB) + sub * SUB;                // output row base

    const float* __restrict__ xim = x + (size_t)bc * (IMG * IMG);
    float* __restrict__ oim = out + (size_t)bc * (OUTW * OUTW);

    // Per-thread constant load bases + edge flags (branchless clamp).
    const int cbase = 4 * j;
    const int bl0 = max(cbase - 4, 0);        // only j=0 OOB-low
    const int bl2 = min(cbase + 4, IMG - 4);  // only j=127 OOB-high
    const int bl3 = min(cbase + 8, IMG - 4);  // j=126,127 OOB-high
    const bool lo0 = (cbase - 4 < 0);
    const bool hi2 = (cbase + 4 > IMG - 4);
    const bool hi3 = (cbase + 8 > IMG - 4);

    float4 ring[KS];
#pragma unroll
    for (int k = 0; k < KS; ++k) ring[k] = make_float4(0.f, 0.f, 0.f, 0.f);
    float4 V = make_float4(0.f, 0.f, 0.f, 0.f);

    float4 P[2][4];  // ping-pong row buffers (all indices compile-time)

#define LOADROW(s_, d_)                                                    \
    {                                                                      \
        const int ri_ = min(max(rb + (s_) - MEAN, 0), IMG - 1);            \
        const float* __restrict__ rp_ = xim + ri_ * IMG;                   \
        P[d_][0] = *(const float4*)(rp_ + bl0);                            \
        P[d_][1] = *(const float4*)(rp_ + cbase);                          \
        P[d_][2] = *(const float4*)(rp_ + bl2);                            \
        P[d_][3] = *(const float4*)(rp_ + bl3);                            \
    }

    LOADROW(0, 0)

#pragma unroll
    for (int s = 0; s < TSTREAM; ++s) {
        const int cur = s & 1;
        float4 v0 = P[cur][0], v1 = P[cur][1], v2 = P[cur][2], v3 = P[cur][3];

        // Issue next row's loads before consuming this row (2-stage pipeline).
        if (s + 1 < TSTREAM) LOADROW(s + 1, cur ^ 1)

        if (lo0) v0 = make_float4(v0.x, v0.x, v0.x, v0.x);  // replicate col 0
        if (hi2) v2 = make_float4(v2.w, v2.w, v2.w, v2.w);  // replicate col 511
        const float w12 = hi3 ? v3.w : v3.x;                // col min(4j+8,511)

        // Horizontal 10-sums for 4 outputs: tree sum + parallel sliding diffs.
        const float S = ((v0.x + v0.y) + (v0.z + v0.w))
                      + ((v1.x + v1.y) + (v1.z + v1.w))
                      + (v2.x + v2.y);
        const float d1  = v2.z - v0.x;
        const float d2  = v2.w - v0.y;
        const float d3  = w12  - v0.z;
        const float d12 = d1 + d2;
        float4 H;
        H.x = S;
        H.y = S + d1;
        H.z = S + d12;
        H.w = S + (d12 + d3);

        // Vertical ring update (static index after unroll).
        const int u = s % KS;
        V.x += H.x - ring[u].x;
        V.y += H.y - ring[u].y;
        V.z += H.z - ring[u].z;
        V.w += H.w - ring[u].w;
        ring[u] = H;

        if (s >= KS - 1) {
            const int i = rb + s - (KS - 1);
            if (i < OUTW) {                      // only last band's last row fails
                float* op = oim + (size_t)i * OUTW + cbase;
                op[0] = fmaf(V.x, -0.5f, 50.0f);
                op[1] = fmaf(V.y, -0.5f, 50.0f);
                op[2] = fmaf(V.z, -0.5f, 50.0f);
                if (cbase + 3 < OUTW) op[3] = fmaf(V.w, -0.5f, 50.0f);
            }
        }
    }
#undef LOADROW
}

extern "C" void kernel_launch(void* const* d_in, const int* in_sizes, int n_in,
                              void* d_out, int out_size, void* d_ws, size_t ws_size,
                              hipStream_t stream) {
    const float* x = (const float*)d_in[0];
    float* out = (float*)d_out;

    dim3 block(256, 1, 1);
    dim3 grid(NBANDS, NIMG, 1);   // 16 x 96 = 1536 blocks
    onedilate_kernel<<<grid, block, 0, stream>>>(x, out);
}